// Round 11
// baseline (501.025 us; speedup 1.0000x reference)
//
#include <hip/hip_runtime.h>
#include <hip/hip_fp16.h>
#include <math.h>

#define BQ 4
#define LQ 4096
#define DM 192
#define DIP 1030
#define DSSM 384
#define DST 128
#define CCH 646
#define CH640 640
#define NHD 6
#define KDIR 4
#define NCH 16
#define CLEN 256
#define UH_ELEMS (16384 * 192)
#define WT_ELEMS (1152 * 192)
#define WO_ELEMS (192 * 384)

using half8 = __attribute__((ext_vector_type(8))) _Float16;
using half4 = __attribute__((ext_vector_type(4))) _Float16;
using f32x4 = __attribute__((ext_vector_type(4))) float;

// Transpose-staging layout: row stride 72 halves (36 dwords = +4 bank rotation/row)
// + XOR of s-octet with row-octet. Conflict-free b16 scatter-writes AND b128 reads.
#define XWI(pp, ss) ((pp) * 72 + ((((ss) >> 3) ^ ((pp) >> 3)) << 3) + ((ss) & 7))
#define XW2(n, ss) ((n) * 72 + (((((ss) >> 3) ^ ((n) >> 3)) & 7) << 3) + ((ss) & 7))

__device__ __forceinline__ int pixof(int k, int t) {
  switch (k) {
    case 0: return t;
    case 1: return ((t & 63) << 6) | (t >> 6);
    case 2: return 4095 - t;
    default: { int tp = 4095 - t; return ((tp & 63) << 6) | (tp >> 6); }
  }
}

__device__ __forceinline__ float softplusf(float x) {
  return (x > 20.f) ? x : log1pf(expf(x));
}
__device__ __forceinline__ float siluf(float x) {
  return x / (1.f + __expf(-x));
}

// ---- 0. convert u -> fp16; W_in -> fp16 T [1152][192]; W_out -> fp16 T [192][384] ----
__global__ void k_cvt(const float* __restrict__ u, const float* __restrict__ W,
                      const float* __restrict__ Wout,
                      _Float16* __restrict__ uh, _Float16* __restrict__ whT,
                      _Float16* __restrict__ woT) {
  int idx = blockIdx.x * 256 + threadIdx.x;
  if (idx < UH_ELEMS) uh[idx] = (_Float16)u[idx];
  int widx = idx - UH_ELEMS;
  if (widx >= 0 && widx < WT_ELEMS) {
    int n = widx / 192, kk = widx - n * 192;
    whT[widx] = (n < DIP) ? (_Float16)W[(size_t)kk * DIP + n] : (_Float16)0.f;
  }
  int wo = idx - UH_ELEMS - WT_ELEMS;
  if (wo >= 0 && wo < WO_ELEMS) {
    int n = wo / 384, kk = wo - n * 384;
    woT[wo] = (_Float16)Wout[(size_t)kk * DM + n];
  }
}

// ---- 1. in_proj via fp16 MFMA: (16384,192)@(192,1152) -> zh | xbch | xdt32 ----
__global__ __launch_bounds__(256) void k_inproj(
    const _Float16* __restrict__ uh, const _Float16* __restrict__ whT,
    __half* __restrict__ zh, __half* __restrict__ xbch, float* __restrict__ xdt32) {
  __shared__ __align__(16) _Float16 sA[128 * 72];
  __shared__ __align__(16) _Float16 sB[128 * 72];
  int nt = blockIdx.x, mt = blockIdx.y;
  int m0 = mt * 128, n0 = nt * 128;
  int t = threadIdx.x, lane = t & 63, w = t >> 6;
  int acol = lane & 15, koff = (lane >> 4) * 8;
  int wr = w >> 1, wc = w & 1;
  f32x4 zz = {0.f, 0.f, 0.f, 0.f};
  f32x4 acc[4][4];
#pragma unroll
  for (int fr = 0; fr < 4; ++fr)
#pragma unroll
    for (int fc = 0; fc < 4; ++fc) acc[fr][fc] = zz;
  for (int kk = 0; kk < 3; ++kk) {
    if (kk) __syncthreads();
#pragma unroll
    for (int i = 0; i < 4; ++i) {
      int task = t + i * 256;
      int row = task >> 3, oct = task & 7;
      *(half8*)&sA[row * 72 + oct * 8] =
          *(const half8*)&uh[(size_t)(m0 + row) * 192 + kk * 64 + oct * 8];
      *(half8*)&sB[row * 72 + oct * 8] =
          *(const half8*)&whT[(size_t)(n0 + row) * 192 + kk * 64 + oct * 8];
    }
    __syncthreads();
#pragma unroll
    for (int ks = 0; ks < 2; ++ks) {
      half8 af[4], bf[4];
#pragma unroll
      for (int f = 0; f < 4; ++f) {
        af[f] = *(const half8*)&sA[(wr * 64 + f * 16 + acol) * 72 + ks * 32 + koff];
        bf[f] = *(const half8*)&sB[(wc * 64 + f * 16 + acol) * 72 + ks * 32 + koff];
      }
#pragma unroll
      for (int fr = 0; fr < 4; ++fr)
#pragma unroll
        for (int fc = 0; fc < 4; ++fc)
          acc[fr][fc] = __builtin_amdgcn_mfma_f32_16x16x32_f16(af[fr], bf[fc], acc[fr][fc], 0, 0, 0);
    }
  }
  int rb = (lane >> 4) * 4;
#pragma unroll
  for (int fr = 0; fr < 4; ++fr) {
#pragma unroll
    for (int fc = 0; fc < 4; ++fc) {
      int n = n0 + wc * 64 + fc * 16 + acol;
#pragma unroll
      for (int r = 0; r < 4; ++r) {
        int m = m0 + wr * 64 + fr * 16 + rb + r;
        float v = acc[fr][fc][r];
        if (n < DSSM) zh[(size_t)m * DSSM + n] = (__half)v;
        else if (n < 1024) xbch[(size_t)m * CH640 + (n - DSSM)] = (__half)v;
        else if (n < DIP) xdt32[(size_t)m * NHD + (n - 1024)] = v;
      }
    }
  }
}

// ---- 2. depthwise 3x3 conv + bias + SiLU (half2-vectorized) ----
__global__ void k_conv(const __half* __restrict__ xbch, const float* __restrict__ xdt,
                       const float* __restrict__ cw, const float* __restrict__ cb,
                       __half* __restrict__ convh, float* __restrict__ dtraw) {
  int pid = blockIdx.x;  // b*4096 + p
  int b = pid >> 12, p = pid & 4095;
  int y = p >> 6, x = p & 63;
  int t = threadIdx.x;
  const __half2* baseh2 = (const __half2*)(xbch + (size_t)b * LQ * CH640);
  __half2* outh2 = (__half2*)(convh + (size_t)pid * CH640);
  for (int pc = t; pc < 320; pc += 256) {
    int c0 = pc * 2;
    float s0 = 0.f, s1 = 0.f;
#pragma unroll
    for (int ky = 0; ky < 3; ++ky) {
      int yy = y + ky - 1;
      if (yy < 0 || yy > 63) continue;
#pragma unroll
      for (int kx = 0; kx < 3; ++kx) {
        int xx = x + kx - 1;
        if (xx < 0 || xx > 63) continue;
        __half2 v = baseh2[(size_t)(yy * 64 + xx) * 320 + pc];
        int wi = ky * 3 + kx;
        s0 += (float)v.x * cw[c0 * 9 + wi];
        s1 += (float)v.y * cw[(c0 + 1) * 9 + wi];
      }
    }
    __half2 o;
    o.x = (__half)siluf(s0 + cb[c0]);
    o.y = (__half)siluf(s1 + cb[c0 + 1]);
    outh2[pc] = o;
  }
  if (t < NHD) {
    const float* based = xdt + (size_t)b * LQ * NHD;
    float s = 0.f;
#pragma unroll
    for (int ky = 0; ky < 3; ++ky) {
      int yy = y + ky - 1;
      if (yy < 0 || yy > 63) continue;
#pragma unroll
      for (int kx = 0; kx < 3; ++kx) {
        int xx = x + kx - 1;
        if (xx < 0 || xx > 63) continue;
        s += based[(size_t)(yy * 64 + xx) * NHD + t] * cw[(CH640 + t) * 9 + ky * 3 + kx];
      }
    }
    dtraw[(size_t)pid * NHD + t] = siluf(s + cb[CH640 + t]);
  }
}

// ---- 3. dt softplus + per-chunk cumsum of dA (fp32 path) ----
__global__ void k_prep(const float* __restrict__ dtraw, const float* __restrict__ dt_bias,
                       const float* __restrict__ A_logs,
                       float* __restrict__ dtb, float* __restrict__ dacb) {
  __shared__ float sb[CLEN];
  int z = blockIdx.x, k = blockIdx.y, b = blockIdx.z;
  int s = threadIdx.x;
  int pixel = pixof(k, z * CLEN + s);
  const float* row = dtraw + ((size_t)(b * LQ + pixel)) * NHD;
  float raw[NHD];
#pragma unroll
  for (int h = 0; h < NHD; ++h) raw[h] = row[h];
  size_t base = (((size_t)(b * KDIR + k) * NCH + z) * NHD) * CLEN;
  for (int h = 0; h < NHD; ++h) {
    float dtv = softplusf(raw[h] + dt_bias[k * NHD + h]);
    float dA = dtv * (-expf(A_logs[k * NHD + h]));
    sb[s] = dA;
    __syncthreads();
    for (int off = 1; off < CLEN; off <<= 1) {
      float v = (s >= off) ? sb[s - off] : 0.f;
      __syncthreads();
      sb[s] += v;
      __syncthreads();
    }
    dtb[base + (size_t)h * CLEN + s] = dtv;
    dacb[base + (size_t)h * CLEN + s] = sb[s];
    __syncthreads();
  }
}

// ---- 4. CB = C @ B^T via fp16 MFMA, lower-triangle 64x64 tiles, fp16 out ----
__global__ __launch_bounds__(256, 4) void k_cb(const _Float16* __restrict__ convh,
                                               _Float16* __restrict__ cbuf) {
  __shared__ __align__(16) char smem[34816];
  _Float16* sCt = (_Float16*)smem;             // [64][136]
  _Float16* sBt = (_Float16*)(smem + 17408);   // [64][136]
  int pi = blockIdx.x, z = blockIdx.y, bk = blockIdx.z;
  int b = bk >> 2, kd = bk & 3;
  int SI = 0;
  while ((SI + 1) * (SI + 2) / 2 <= pi) ++SI;
  int SJ = pi - SI * (SI + 1) / 2;
  int t = threadIdx.x, lane = t & 63, w = t >> 6;
  int acol = lane & 15, koff = (lane >> 4) * 8;
  int R = w * 16, arow = R + acol, rbase = R + (lane >> 4) * 4;
  const _Float16* convb = convh + (size_t)b * LQ * CH640;
  for (int i = 0; i < 4; ++i) {
    int c = t + i * 256;
    int row = c >> 4, seg = c & 15;
    int pc = pixof(kd, z * CLEN + SI * 64 + row);
    *(half8*)&sCt[row * 136 + seg * 8] =
        *(const half8*)&convb[(size_t)pc * CH640 + (DSSM + DST) + seg * 8];
    int pbx = pixof(kd, z * CLEN + SJ * 64 + row);
    *(half8*)&sBt[row * 136 + seg * 8] =
        *(const half8*)&convb[(size_t)pbx * CH640 + DSSM + seg * 8];
  }
  __syncthreads();
  f32x4 zz = {0.f, 0.f, 0.f, 0.f};
  f32x4 acc[4] = {zz, zz, zz, zz};
  for (int ks = 0; ks < 4; ++ks) {
    half8 a = *(const half8*)&sCt[arow * 136 + ks * 32 + koff];
#pragma unroll
    for (int cg = 0; cg < 4; ++cg) {
      half8 bf = *(const half8*)&sBt[(cg * 16 + acol) * 136 + ks * 32 + koff];
      acc[cg] = __builtin_amdgcn_mfma_f32_16x16x32_f16(a, bf, acc[cg], 0, 0, 0);
    }
  }
  size_t base = ((size_t)(bk * NCH + z) * 10 + pi) * 4096;
#pragma unroll
  for (int cg = 0; cg < 4; ++cg)
#pragma unroll
    for (int r = 0; r < 4; ++r)
      cbuf[base + (size_t)(rbase + r) * 64 + cg * 16 + acol] = (_Float16)acc[cg][r];
}

// ---- 4b. diag tiles: dbuf = CB_diag (*) exp(dac_sl - dac_ss), masked, per head ----
__global__ void k_diag(const _Float16* __restrict__ cbuf, const float* __restrict__ dacb,
                       _Float16* __restrict__ dbuf) {
  __shared__ float sd[64];
  int hs = blockIdx.x;        // 24 = si*6 + h
  int si = hs / 6, h = hs % 6;
  int z = blockIdx.y, bk = blockIdx.z;
  int t = threadIdx.x;
  if (t < 64) sd[t] = dacb[(((size_t)bk * NCH + z) * NHD + h) * CLEN + si * 64 + t];
  __syncthreads();
  size_t cb = ((size_t)(bk * NCH + z) * 10 + si * (si + 1) / 2 + si) * 4096;
  size_t db = (((size_t)(bk * NCH + z) * 4 + si) * NHD + h) * 4096;
#pragma unroll
  for (int i = 0; i < 16; ++i) {
    int e = t + i * 256;
    int sl = e >> 6, ss = e & 63;
    _Float16 v = (_Float16)0.f;
    if (ss <= sl) v = (_Float16)((float)cbuf[cb + e] * __expf(sd[sl] - sd[ss]));
    dbuf[db + e] = v;
  }
}

// ---- 4c. xwnT[bkz][tile][h][p][ss] = x*dt*exp(dac_end_tile - dac_ss)  (fp16, B-frag layout) ----
__global__ void k_xw(const _Float16* __restrict__ convh, const float* __restrict__ dtb,
                     const float* __restrict__ dacb, _Float16* __restrict__ xwnT) {
  __shared__ __align__(16) _Float16 sA[64 * 72];
  int th = blockIdx.x;  // 24 = tile*6 + h
  int tile = th / 6, h = th % 6;
  int z = blockIdx.y, bk = blockIdx.z;
  int b = bk >> 2, kd = bk & 3;
  int t = threadIdx.x;
  size_t dbase = (((size_t)bk * NCH + z) * NHD + h) * CLEN;
  float dacE = dacb[dbase + tile * 64 + 63];
  const _Float16* convb = convh + (size_t)b * LQ * CH640;
#pragma unroll
  for (int i = 0; i < 2; ++i) {
    int c = t + i * 256;
    int ss = c >> 3, pp0 = (c & 7) * 8;
    int sg = tile * 64 + ss;
    int px = pixof(kd, z * CLEN + sg);
    half8 xv = *(const half8*)&convb[(size_t)px * CH640 + h * 64 + pp0];
    float f = dtb[dbase + sg] * __expf(dacE - dacb[dbase + sg]);
#pragma unroll
    for (int u = 0; u < 8; ++u) sA[XWI(pp0 + u, ss)] = (_Float16)((float)xv[u] * f);
  }
  __syncthreads();
  size_t obase = (((size_t)(bk * NCH + z) * 4 + tile) * NHD + h) * 4096;
#pragma unroll
  for (int i = 0; i < 2; ++i) {
    int task = t + i * 256;
    int p = task >> 3, q = task & 7;
    half8 v = *(const half8*)&sA[p * 72 + (q << 3)];
    int ss0 = (q ^ (p >> 3)) << 3;
    *(half8*)&xwnT[obase + p * 64 + ss0] = v;
  }
}

// ---- 5. chunk states via fp16 MFMA -> statesT[p][n] fp16 ----
__global__ __launch_bounds__(256, 4) void k_states(
    const _Float16* __restrict__ convh, const float* __restrict__ dtb,
    const float* __restrict__ dacb, _Float16* __restrict__ statesT) {
  __shared__ __align__(16) _Float16 sA[64 * 72];    // XW^T [p][s] swizzled
  __shared__ __align__(16) _Float16 sB2[128 * 72];  // B^T [n][s] swizzled
  __shared__ float sFac[CLEN];
  int h = blockIdx.x, z = blockIdx.y, bk = blockIdx.z;
  int b = bk >> 2, kd = bk & 3;
  int t = threadIdx.x, lane = t & 63, w = t >> 6;
  int acol = lane & 15, koct = lane >> 4;
  size_t dbase = (((size_t)bk * NCH + z) * NHD + h) * CLEN;
  {
    float dac_last = dacb[dbase + CLEN - 1];
    sFac[t] = dtb[dbase + t] * __expf(dac_last - dacb[dbase + t]);
  }
  __syncthreads();
  const _Float16* convb = convh + (size_t)b * LQ * CH640;
  f32x4 zz = {0.f, 0.f, 0.f, 0.f};
  f32x4 acc[8] = {zz, zz, zz, zz, zz, zz, zz, zz};
  for (int st = 0; st < 4; ++st) {
    if (st) __syncthreads();
#pragma unroll
    for (int i = 0; i < 2; ++i) {
      int c = t + i * 256;
      int ss = c >> 3, pp0 = (c & 7) * 8;
      int sg = st * 64 + ss;
      int px = pixof(kd, z * CLEN + sg);
      half8 xv = *(const half8*)&convb[(size_t)px * CH640 + h * 64 + pp0];
      float f = sFac[sg];
#pragma unroll
      for (int u = 0; u < 8; ++u) sA[XWI(pp0 + u, ss)] = (_Float16)((float)xv[u] * f);
    }
#pragma unroll
    for (int i = 0; i < 4; ++i) {
      int c = t + i * 256;
      int ss = c >> 4, n0 = (c & 15) * 8;
      int sg = st * 64 + ss;
      int px = pixof(kd, z * CLEN + sg);
      half8 bv = *(const half8*)&convb[(size_t)px * CH640 + DSSM + n0];
#pragma unroll
      for (int u = 0; u < 8; ++u) sB2[XW2(n0 + u, ss)] = bv[u];
    }
    __syncthreads();
#pragma unroll
    for (int ks = 0; ks < 2; ++ks) {
      int kso = ks * 4 + koct;
      int arow = w * 16 + acol;
      half8 a = *(const half8*)&sA[arow * 72 + ((kso ^ (arow >> 3)) << 3)];
#pragma unroll
      for (int nf = 0; nf < 8; ++nf) {
        int col = nf * 16 + acol;
        half8 bf = *(const half8*)&sB2[col * 72 + (((kso ^ (col >> 3)) & 7) << 3)];
        acc[nf] = __builtin_amdgcn_mfma_f32_16x16x32_f16(a, bf, acc[nf], 0, 0, 0);
      }
    }
  }
  size_t sbase = (((size_t)bk * NCH + z) * NHD + h) * (128 * 64);
  int rbase = koct * 4;
#pragma unroll
  for (int nf = 0; nf < 8; ++nf) {
    int col = nf * 16 + acol;
#pragma unroll
    for (int r = 0; r < 4; ++r)
      statesT[sbase + (size_t)(w * 16 + rbase + r) * 128 + col] = (_Float16)acc[nf][r];
  }
}

// ---- 6. inter-chunk scan (in place on fp16, fp32 carry) ----
__global__ void k_scan(_Float16* __restrict__ states, const float* __restrict__ dacb) {
  int h = blockIdx.x, k = blockIdx.y, b = blockIdx.z;
  int bk = b * KDIR + k;
  int t = threadIdx.x;
  float carry[32];
#pragma unroll
  for (int j = 0; j < 32; ++j) carry[j] = 0.f;
  for (int z = 0; z < NCH; ++z) {
    float cd = __expf(dacb[(((size_t)bk * NCH + z) * NHD + h) * CLEN + (CLEN - 1)]);
    size_t sbase = (((size_t)bk * NCH + z) * NHD + h) * (128 * 64);
#pragma unroll
    for (int j = 0; j < 32; ++j) {
      size_t idx = sbase + (size_t)j * 256 + t;
      float sv = (float)states[idx];
      states[idx] = (_Float16)carry[j];
      carry[j] = carry[j] * cd + sv;
    }
  }
}

// ---- 7. y via fp16 MFMA: 1 barrier, LDS only for diag XW; B-frags from global xwnT ----
__global__ __launch_bounds__(256, 4) void k_y(
    const _Float16* __restrict__ convh, const float* __restrict__ dtb,
    const float* __restrict__ dacb, const _Float16* __restrict__ cbuf,
    const _Float16* __restrict__ prevT, const _Float16* __restrict__ dbuf,
    const _Float16* __restrict__ xwnT, const float* __restrict__ Ds,
    _Float16* __restrict__ ybuf) {
  __shared__ __align__(16) _Float16 sXW[64 * 72];

  int wg = blockIdx.x;  // 6144 = 8 XCD * 768
  int xid = (wg & 7) * 768 + (wg >> 3);
  int grp = xid / 24, i24 = xid % 24;
  int h = i24 >> 2, si_t = i24 & 3;
  int bk = grp >> 4, z = grp & 15;
  int b = bk >> 2, kd = bk & 3;
  int t = threadIdx.x, lane = t & 63, w = t >> 6;
  int acol = lane & 15, koff = (lane >> 4) * 8;
  int R = w * 16, arow = R + acol, rbase = R + (lane >> 4) * 4;

  size_t dbase = (((size_t)bk * NCH + z) * NHD + h) * CLEN;
  const _Float16* convb = convh + (size_t)b * LQ * CH640;

  // ---- diag XW staging (x*dt, decay lives in dbuf) — issued early ----
#pragma unroll
  for (int i = 0; i < 2; ++i) {
    int c = t + i * 256;
    int ss = c >> 3, pp0 = (c & 7) * 8;
    int sg = si_t * 64 + ss;
    int px = pixof(kd, z * CLEN + sg);
    half8 xv = *(const half8*)&convb[(size_t)px * CH640 + h * 64 + pp0];
    float f = dtb[dbase + sg];
#pragma unroll
    for (int u = 0; u < 8; ++u)
      sXW[XWI(pp0 + u, ss)] = (_Float16)((float)xv[u] * f);
  }

  // ---- per-thread row scalars ----
  float ref = dacb[dbase + si_t * 64];
  float4 dv = *(const float4*)&dacb[dbase + si_t * 64 + rbase];
  float eD[4], rsv[4];
  {
    float dvv[4] = {dv.x, dv.y, dv.z, dv.w};
#pragma unroll
    for (int r = 0; r < 4; ++r) {
      eD[r] = __expf(dvv[r]);
      rsv[r] = __expf(dvv[r] - ref);
    }
  }

  f32x4 zz = {0.f, 0.f, 0.f, 0.f};
  f32x4 accE[4] = {zz, zz, zz, zz};
  f32x4 accI[4] = {zz, zz, zz, zz};
  // ---- y_inter: C and prev fragments straight from global ----
  const _Float16* pbp = prevT + (((size_t)bk * NCH + z) * NHD + h) * (128 * 64);
  int pxa = pixof(kd, z * CLEN + si_t * 64 + arow);
#pragma unroll
  for (int ks = 0; ks < 4; ++ks) {
    half8 a = *(const half8*)&convb[(size_t)pxa * CH640 + (DSSM + DST) + ks * 32 + koff];
#pragma unroll
    for (int cg = 0; cg < 4; ++cg) {
      half8 bf = *(const half8*)&pbp[(size_t)(cg * 16 + acol) * 128 + ks * 32 + koff];
      accE[cg] = __builtin_amdgcn_mfma_f32_16x16x32_f16(a, bf, accE[cg], 0, 0, 0);
    }
  }
  // ---- y_intra off-diagonal: B from global xwnT, uniform scalar folded into A ----
  for (int SJ = 0; SJ < si_t; ++SJ) {
    _Float16 suh = (_Float16)__expf(ref - dacb[dbase + SJ * 64 + 63]);
    size_t cbase = ((size_t)(bk * NCH + z) * 10 + si_t * (si_t + 1) / 2 + SJ) * 4096;
    const _Float16* xwb = xwnT + (((size_t)(bk * NCH + z) * 4 + SJ) * NHD + h) * 4096;
#pragma unroll
    for (int ks = 0; ks < 2; ++ks) {
      half8 a = *(const half8*)&cbuf[cbase + (size_t)arow * 64 + ks * 32 + koff];
#pragma unroll
      for (int u = 0; u < 8; ++u) a[u] = a[u] * suh;
#pragma unroll
      for (int cg = 0; cg < 4; ++cg) {
        int col = cg * 16 + acol;
        half8 bf = *(const half8*)&xwb[(size_t)col * 64 + ks * 32 + koff];
        accI[cg] = __builtin_amdgcn_mfma_f32_16x16x32_f16(a, bf, accI[cg], 0, 0, 0);
      }
    }
  }
  // scale off-diag partial by per-row decay
#pragma unroll
  for (int cg = 0; cg < 4; ++cg)
#pragma unroll
    for (int r = 0; r < 4; ++r) accI[cg][r] *= rsv[r];
  __syncthreads();  // diag staging complete
  // ---- diagonal tile: A' from dbuf, B from LDS ----
  {
    size_t db = (((size_t)(bk * NCH + z) * 4 + si_t) * NHD + h) * 4096;
#pragma unroll
    for (int ks = 0; ks < 2; ++ks) {
      half8 a = *(const half8*)&dbuf[db + (size_t)arow * 64 + ks * 32 + koff];
      int kso = ks * 4 + (lane >> 4);
#pragma unroll
      for (int cg = 0; cg < 4; ++cg) {
        int col = cg * 16 + acol;
        half8 bf = *(const half8*)&sXW[col * 72 + ((kso ^ (col >> 3)) << 3)];
        accI[cg] = __builtin_amdgcn_mfma_f32_16x16x32_f16(a, bf, accI[cg], 0, 0, 0);
      }
    }
  }
  // ---- write: y = accI + exp(dac)*accE + D*x ----
  float dsv = Ds[kd * NHD + h];
#pragma unroll
  for (int cg = 0; cg < 4; ++cg) {
    int col = cg * 16 + acol;
#pragma unroll
    for (int r = 0; r < 4; ++r) {
      int row = rbase + r;
      int tg = z * CLEN + si_t * 64 + row;
      int px = pixof(kd, tg);
      float xv = (float)convb[(size_t)px * CH640 + h * 64 + col];
      float yv = accI[cg][r] + eD[r] * accE[cg][r] + dsv * xv;
      ybuf[((size_t)bk * LQ + tg) * DSSM + h * 64 + col] = (_Float16)yv;
    }
  }
}

// ---- 8. gather + gated RMSNorm + out projection via MFMA (32 rows / block) ----
__global__ __launch_bounds__(256) void k_final(
    const _Float16* __restrict__ yb, const _Float16* __restrict__ zh,
    const float* __restrict__ norm_w, const _Float16* __restrict__ woT,
    float* __restrict__ out) {
  __shared__ __align__(16) _Float16 sG[32 * 392];
  int m0 = blockIdx.x * 32;
  int t = threadIdx.x;
  int row = t >> 3, q = t & 7;
  int m = m0 + row, b = m >> 12, px = m & 4095;
  int tr = ((px & 63) << 6) | (px >> 6);
  int t0 = px, t1 = tr, t2 = 4095 - px, t3 = 4095 - tr;
  size_t b4 = (size_t)b * 4;
  float gbuf[48];
  float sumsq = 0.f;
#pragma unroll
  for (int i = 0; i < 6; ++i) {
    int c0 = q * 48 + i * 8;
    half8 y0 = *(const half8*)&yb[((b4 + 0) * LQ + t0) * DSSM + c0];
    half8 y1 = *(const half8*)&yb[((b4 + 1) * LQ + t1) * DSSM + c0];
    half8 y2 = *(const half8*)&yb[((b4 + 2) * LQ + t2) * DSSM + c0];
    half8 y3 = *(const half8*)&yb[((b4 + 3) * LQ + t3) * DSSM + c0];
    half8 zv8 = *(const half8*)&zh[(size_t)m * DSSM + c0];
#pragma unroll
    for (int u = 0; u < 8; ++u) {
      float zv = (float)zv8[u];
      float g = ((float)y0[u] + (float)y1[u] + (float)y2[u] + (float)y3[u]) *
                (zv / (1.f + __expf(-zv)));
      gbuf[i * 8 + u] = g;
      sumsq += g * g;
    }
  }
  sumsq += __shfl_xor(sumsq, 1);
  sumsq += __shfl_xor(sumsq, 2);
  sumsq += __shfl_xor(sumsq, 4);
  float rstd = rsqrtf(sumsq / (float)DSSM + 1e-5f);
#pragma unroll
  for (int i = 0; i < 6; ++i) {
    int c0 = q * 48 + i * 8;
    half8 gv;
#pragma unroll
    for (int u = 0; u < 8; ++u)
      gv[u] = (_Float16)(gbuf[i * 8 + u] * rstd * norm_w[c0 + u]);
    *(half8*)&sG[row * 392 + c0] = gv;
  }
  __syncthreads();
  int lane = t & 63, w = t >> 6;
  int acol = lane & 15, koff = (lane >> 4) * 8;
  int rt = (w & 1) * 16, cb0 = (w >> 1) * 96;
  f32x4 zz = {0.f, 0.f, 0.f, 0.f};
  f32x4 acc[6] = {zz, zz, zz, zz, zz, zz};
  for (int ks = 0; ks < 12; ++ks) {
    half8 a = *(const half8*)&sG[(rt + acol) * 392 + ks * 32 + koff];
#pragma unroll
    for (int nf = 0; nf < 6; ++nf) {
      half8 bf = *(const half8*)&woT[(size_t)(cb0 + nf * 16 + acol) * 384 + ks * 32 + koff];
      acc[nf] = __builtin_amdgcn_mfma_f32_16x16x32_f16(a, bf, acc[nf], 0, 0, 0);
    }
  }
  int rb = (lane >> 4) * 4;
#pragma unroll
  for (int nf = 0; nf < 6; ++nf) {
    int n = cb0 + nf * 16 + acol;
#pragma unroll
    for (int r = 0; r < 4; ++r)
      out[(size_t)(m0 + rt + rb + r) * DM + n] = acc[nf][r];
  }
}

extern "C" void kernel_launch(void* const* d_in, const int* in_sizes, int n_in,
                              void* d_out, int out_size, void* d_ws, size_t ws_size,
                              hipStream_t stream) {
  const float* u = (const float*)d_in[0];
  const float* W_in = (const float*)d_in[1];
  const float* conv_w = (const float*)d_in[2];
  const float* conv_b = (const float*)d_in[3];
  const float* dt_bias = (const float*)d_in[4];
  const float* A_logs = (const float*)d_in[5];
  const float* Ds = (const float*)d_in[6];
  const float* norm_w = (const float*)d_in[7];
  const float* W_out = (const float*)d_in[8];
  float* out = (float*)d_out;

  float* ws = (float*)d_ws;
  size_t off = 0;
  __half* zh = (__half*)(ws + off); off += (size_t)BQ * LQ * DSSM / 2;
  float* scratch = ws + off; off += 1683456;  // uh+whT region, reused for dt bufs
  _Float16* uh = (_Float16*)scratch;
  _Float16* whT = uh + UH_ELEMS;
  float* dtraw = scratch;                                   // alias (uh dead post-inproj)
  float* dtb = scratch + 98304;
  float* dacb = scratch + 98304 + 393216;
  __half* xbch = (__half*)(ws + off); off += (size_t)BQ * LQ * CH640 / 2;
  float* xdt32 = ws + off; off += (size_t)BQ * LQ * NHD;
  __half* convh = (__half*)(ws + off); off += (size_t)BQ * LQ * CH640 / 2;
  _Float16* statesT = (_Float16*)(ws + off); off += (size_t)BQ * KDIR * NCH * NHD * 128 * 64 / 2;
  __half* ybuf = (__half*)(ws + off); off += (size_t)BQ * KDIR * LQ * DSSM / 2;
  _Float16* dbuf = (_Float16*)(ws + off); off += (size_t)BQ * KDIR * NCH * 4 * NHD * 4096 / 2;
  _Float16* woT = (_Float16*)(ws + off); off += WO_ELEMS / 2;
  _Float16* xwnT = (_Float16*)(ws + off); off += (size_t)BQ * KDIR * NCH * 4 * NHD * 4096 / 2;
  _Float16* cbuf = (_Float16*)xbch;  // alias: xbch dead after k_conv

  k_cvt<<<(UH_ELEMS + WT_ELEMS + WO_ELEMS + 255) / 256, 256, 0, stream>>>(u, W_in, W_out, uh, whT, woT);
  k_inproj<<<dim3(9, 128), 256, 0, stream>>>(uh, whT, zh, xbch, xdt32);
  k_conv<<<BQ * LQ, 256, 0, stream>>>(xbch, xdt32, conv_w, conv_b, convh, dtraw);
  k_prep<<<dim3(NCH, KDIR, BQ), 256, 0, stream>>>(dtraw, dt_bias, A_logs, dtb, dacb);
  k_cb<<<dim3(10, NCH, BQ * KDIR), 256, 0, stream>>>((const _Float16*)convh, cbuf);
  k_diag<<<dim3(24, NCH, BQ * KDIR), 256, 0, stream>>>(cbuf, dacb, dbuf);
  k_xw<<<dim3(24, NCH, BQ * KDIR), 256, 0, stream>>>((const _Float16*)convh, dtb, dacb, xwnT);
  k_states<<<dim3(NHD, NCH, BQ * KDIR), 256, 0, stream>>>((const _Float16*)convh, dtb, dacb, statesT);
  k_scan<<<dim3(NHD, KDIR, BQ), 256, 0, stream>>>(statesT, dacb);
  k_y<<<KDIR * NHD * 4 * NCH * BQ, 256, 0, stream>>>((const _Float16*)convh, dtb, dacb,
                                                     (const _Float16*)cbuf, statesT, dbuf,
                                                     xwnT, Ds, (_Float16*)ybuf);
  k_final<<<BQ * LQ / 32, 256, 0, stream>>>((const _Float16*)ybuf, (const _Float16*)zh,
                                            norm_w, woT, out);
}

// Round 12
// 430.324 us; speedup vs baseline: 1.1643x; 1.1643x over previous
//
#include <hip/hip_runtime.h>
#include <hip/hip_fp16.h>
#include <math.h>

#define BQ 4
#define LQ 4096
#define DM 192
#define DIP 1030
#define DSSM 384
#define DST 128
#define CCH 646
#define CH640 640
#define NHD 6
#define KDIR 4
#define NCH 16
#define CLEN 256
#define UH_ELEMS (16384 * 192)
#define WT_ELEMS (1152 * 192)
#define WO_ELEMS (192 * 384)

using half8 = __attribute__((ext_vector_type(8))) _Float16;
using half4 = __attribute__((ext_vector_type(4))) _Float16;
using f32x4 = __attribute__((ext_vector_type(4))) float;

// Transpose-staging layout: row stride 72 halves (36 dwords = +4 bank rotation/row)
// + XOR of s-octet with row-octet. Conflict-free b16 scatter-writes AND b128 reads.
#define XWI(pp, ss) ((pp) * 72 + ((((ss) >> 3) ^ ((pp) >> 3)) << 3) + ((ss) & 7))
#define XW2(n, ss) ((n) * 72 + (((((ss) >> 3) ^ ((n) >> 3)) & 7) << 3) + ((ss) & 7))

__device__ __forceinline__ int pixof(int k, int t) {
  switch (k) {
    case 0: return t;
    case 1: return ((t & 63) << 6) | (t >> 6);
    case 2: return 4095 - t;
    default: { int tp = 4095 - t; return ((tp & 63) << 6) | (tp >> 6); }
  }
}

__device__ __forceinline__ float softplusf(float x) {
  return (x > 20.f) ? x : log1pf(expf(x));
}
__device__ __forceinline__ float siluf(float x) {
  return x / (1.f + __expf(-x));
}

// ---- 0. convert u -> fp16; W_in -> fp16 T [1152][192]; W_out -> fp16 T [192][384] ----
__global__ void k_cvt(const float* __restrict__ u, const float* __restrict__ W,
                      const float* __restrict__ Wout,
                      _Float16* __restrict__ uh, _Float16* __restrict__ whT,
                      _Float16* __restrict__ woT) {
  int idx = blockIdx.x * 256 + threadIdx.x;
  if (idx < UH_ELEMS) uh[idx] = (_Float16)u[idx];
  int widx = idx - UH_ELEMS;
  if (widx >= 0 && widx < WT_ELEMS) {
    int n = widx / 192, kk = widx - n * 192;
    whT[widx] = (n < DIP) ? (_Float16)W[(size_t)kk * DIP + n] : (_Float16)0.f;
  }
  int wo = idx - UH_ELEMS - WT_ELEMS;
  if (wo >= 0 && wo < WO_ELEMS) {
    int n = wo / 384, kk = wo - n * 384;
    woT[wo] = (_Float16)Wout[(size_t)kk * DM + n];
  }
}

// ---- 1. in_proj via fp16 MFMA: (16384,192)@(192,1152) -> zh | xbch | xdt32 ----
__global__ __launch_bounds__(256) void k_inproj(
    const _Float16* __restrict__ uh, const _Float16* __restrict__ whT,
    __half* __restrict__ zh, __half* __restrict__ xbch, float* __restrict__ xdt32) {
  __shared__ __align__(16) _Float16 sA[128 * 72];
  __shared__ __align__(16) _Float16 sB[128 * 72];
  int nt = blockIdx.x, mt = blockIdx.y;
  int m0 = mt * 128, n0 = nt * 128;
  int t = threadIdx.x, lane = t & 63, w = t >> 6;
  int acol = lane & 15, koff = (lane >> 4) * 8;
  int wr = w >> 1, wc = w & 1;
  f32x4 zz = {0.f, 0.f, 0.f, 0.f};
  f32x4 acc[4][4];
#pragma unroll
  for (int fr = 0; fr < 4; ++fr)
#pragma unroll
    for (int fc = 0; fc < 4; ++fc) acc[fr][fc] = zz;
  for (int kk = 0; kk < 3; ++kk) {
    if (kk) __syncthreads();
#pragma unroll
    for (int i = 0; i < 4; ++i) {
      int task = t + i * 256;
      int row = task >> 3, oct = task & 7;
      *(half8*)&sA[row * 72 + oct * 8] =
          *(const half8*)&uh[(size_t)(m0 + row) * 192 + kk * 64 + oct * 8];
      *(half8*)&sB[row * 72 + oct * 8] =
          *(const half8*)&whT[(size_t)(n0 + row) * 192 + kk * 64 + oct * 8];
    }
    __syncthreads();
#pragma unroll
    for (int ks = 0; ks < 2; ++ks) {
      half8 af[4], bf[4];
#pragma unroll
      for (int f = 0; f < 4; ++f) {
        af[f] = *(const half8*)&sA[(wr * 64 + f * 16 + acol) * 72 + ks * 32 + koff];
        bf[f] = *(const half8*)&sB[(wc * 64 + f * 16 + acol) * 72 + ks * 32 + koff];
      }
#pragma unroll
      for (int fr = 0; fr < 4; ++fr)
#pragma unroll
        for (int fc = 0; fc < 4; ++fc)
          acc[fr][fc] = __builtin_amdgcn_mfma_f32_16x16x32_f16(af[fr], bf[fc], acc[fr][fc], 0, 0, 0);
    }
  }
  int rb = (lane >> 4) * 4;
#pragma unroll
  for (int fr = 0; fr < 4; ++fr) {
#pragma unroll
    for (int fc = 0; fc < 4; ++fc) {
      int n = n0 + wc * 64 + fc * 16 + acol;
#pragma unroll
      for (int r = 0; r < 4; ++r) {
        int m = m0 + wr * 64 + fr * 16 + rb + r;
        float v = acc[fr][fc][r];
        if (n < DSSM) zh[(size_t)m * DSSM + n] = (__half)v;
        else if (n < 1024) xbch[(size_t)m * CH640 + (n - DSSM)] = (__half)v;
        else if (n < DIP) xdt32[(size_t)m * NHD + (n - 1024)] = v;
      }
    }
  }
}

// ---- 2. depthwise 3x3 conv + bias + SiLU (half2-vectorized) ----
__global__ void k_conv(const __half* __restrict__ xbch, const float* __restrict__ xdt,
                       const float* __restrict__ cw, const float* __restrict__ cb,
                       __half* __restrict__ convh, float* __restrict__ dtraw) {
  int pid = blockIdx.x;  // b*4096 + p
  int b = pid >> 12, p = pid & 4095;
  int y = p >> 6, x = p & 63;
  int t = threadIdx.x;
  const __half2* baseh2 = (const __half2*)(xbch + (size_t)b * LQ * CH640);
  __half2* outh2 = (__half2*)(convh + (size_t)pid * CH640);
  for (int pc = t; pc < 320; pc += 256) {
    int c0 = pc * 2;
    float s0 = 0.f, s1 = 0.f;
#pragma unroll
    for (int ky = 0; ky < 3; ++ky) {
      int yy = y + ky - 1;
      if (yy < 0 || yy > 63) continue;
#pragma unroll
      for (int kx = 0; kx < 3; ++kx) {
        int xx = x + kx - 1;
        if (xx < 0 || xx > 63) continue;
        __half2 v = baseh2[(size_t)(yy * 64 + xx) * 320 + pc];
        int wi = ky * 3 + kx;
        s0 += (float)v.x * cw[c0 * 9 + wi];
        s1 += (float)v.y * cw[(c0 + 1) * 9 + wi];
      }
    }
    __half2 o;
    o.x = (__half)siluf(s0 + cb[c0]);
    o.y = (__half)siluf(s1 + cb[c0 + 1]);
    outh2[pc] = o;
  }
  if (t < NHD) {
    const float* based = xdt + (size_t)b * LQ * NHD;
    float s = 0.f;
#pragma unroll
    for (int ky = 0; ky < 3; ++ky) {
      int yy = y + ky - 1;
      if (yy < 0 || yy > 63) continue;
#pragma unroll
      for (int kx = 0; kx < 3; ++kx) {
        int xx = x + kx - 1;
        if (xx < 0 || xx > 63) continue;
        s += based[(size_t)(yy * 64 + xx) * NHD + t] * cw[(CH640 + t) * 9 + ky * 3 + kx];
      }
    }
    dtraw[(size_t)pid * NHD + t] = siluf(s + cb[CH640 + t]);
  }
}

// ---- 3. dt softplus + per-chunk cumsum of dA (fp32 path) ----
__global__ void k_prep(const float* __restrict__ dtraw, const float* __restrict__ dt_bias,
                       const float* __restrict__ A_logs,
                       float* __restrict__ dtb, float* __restrict__ dacb) {
  __shared__ float sb[CLEN];
  int z = blockIdx.x, k = blockIdx.y, b = blockIdx.z;
  int s = threadIdx.x;
  int pixel = pixof(k, z * CLEN + s);
  const float* row = dtraw + ((size_t)(b * LQ + pixel)) * NHD;
  float raw[NHD];
#pragma unroll
  for (int h = 0; h < NHD; ++h) raw[h] = row[h];
  size_t base = (((size_t)(b * KDIR + k) * NCH + z) * NHD) * CLEN;
  for (int h = 0; h < NHD; ++h) {
    float dtv = softplusf(raw[h] + dt_bias[k * NHD + h]);
    float dA = dtv * (-expf(A_logs[k * NHD + h]));
    sb[s] = dA;
    __syncthreads();
    for (int off = 1; off < CLEN; off <<= 1) {
      float v = (s >= off) ? sb[s - off] : 0.f;
      __syncthreads();
      sb[s] += v;
      __syncthreads();
    }
    dtb[base + (size_t)h * CLEN + s] = dtv;
    dacb[base + (size_t)h * CLEN + s] = sb[s];
    __syncthreads();
  }
}

// ---- 4. CB = C @ B^T via fp16 MFMA, lower-triangle 64x64 tiles, fp16 out ----
__global__ __launch_bounds__(256, 4) void k_cb(const _Float16* __restrict__ convh,
                                               _Float16* __restrict__ cbuf) {
  __shared__ __align__(16) char smem[34816];
  _Float16* sCt = (_Float16*)smem;             // [64][136]
  _Float16* sBt = (_Float16*)(smem + 17408);   // [64][136]
  int pi = blockIdx.x, z = blockIdx.y, bk = blockIdx.z;
  int b = bk >> 2, kd = bk & 3;
  int SI = 0;
  while ((SI + 1) * (SI + 2) / 2 <= pi) ++SI;
  int SJ = pi - SI * (SI + 1) / 2;
  int t = threadIdx.x, lane = t & 63, w = t >> 6;
  int acol = lane & 15, koff = (lane >> 4) * 8;
  int R = w * 16, arow = R + acol, rbase = R + (lane >> 4) * 4;
  const _Float16* convb = convh + (size_t)b * LQ * CH640;
  for (int i = 0; i < 4; ++i) {
    int c = t + i * 256;
    int row = c >> 4, seg = c & 15;
    int pc = pixof(kd, z * CLEN + SI * 64 + row);
    *(half8*)&sCt[row * 136 + seg * 8] =
        *(const half8*)&convb[(size_t)pc * CH640 + (DSSM + DST) + seg * 8];
    int pbx = pixof(kd, z * CLEN + SJ * 64 + row);
    *(half8*)&sBt[row * 136 + seg * 8] =
        *(const half8*)&convb[(size_t)pbx * CH640 + DSSM + seg * 8];
  }
  __syncthreads();
  f32x4 zz = {0.f, 0.f, 0.f, 0.f};
  f32x4 acc[4] = {zz, zz, zz, zz};
  for (int ks = 0; ks < 4; ++ks) {
    half8 a = *(const half8*)&sCt[arow * 136 + ks * 32 + koff];
#pragma unroll
    for (int cg = 0; cg < 4; ++cg) {
      half8 bf = *(const half8*)&sBt[(cg * 16 + acol) * 136 + ks * 32 + koff];
      acc[cg] = __builtin_amdgcn_mfma_f32_16x16x32_f16(a, bf, acc[cg], 0, 0, 0);
    }
  }
  size_t base = ((size_t)(bk * NCH + z) * 10 + pi) * 4096;
#pragma unroll
  for (int cg = 0; cg < 4; ++cg)
#pragma unroll
    for (int r = 0; r < 4; ++r)
      cbuf[base + (size_t)(rbase + r) * 64 + cg * 16 + acol] = (_Float16)acc[cg][r];
}

// ---- 4b. diag tiles: dbuf = CB_diag (*) exp(dac_sl - dac_ss), masked, per head ----
__global__ void k_diag(const _Float16* __restrict__ cbuf, const float* __restrict__ dacb,
                       _Float16* __restrict__ dbuf) {
  __shared__ float sd[64];
  int hs = blockIdx.x;        // 24 = si*6 + h
  int si = hs / 6, h = hs % 6;
  int z = blockIdx.y, bk = blockIdx.z;
  int t = threadIdx.x;
  if (t < 64) sd[t] = dacb[(((size_t)bk * NCH + z) * NHD + h) * CLEN + si * 64 + t];
  __syncthreads();
  size_t cb = ((size_t)(bk * NCH + z) * 10 + si * (si + 1) / 2 + si) * 4096;
  size_t db = (((size_t)(bk * NCH + z) * 4 + si) * NHD + h) * 4096;
#pragma unroll
  for (int i = 0; i < 16; ++i) {
    int e = t + i * 256;
    int sl = e >> 6, ss = e & 63;
    _Float16 v = (_Float16)0.f;
    if (ss <= sl) v = (_Float16)((float)cbuf[cb + e] * __expf(sd[sl] - sd[ss]));
    dbuf[db + e] = v;
  }
}

// ---- 5. chunk states via fp16 MFMA -> statesT[p][n] fp16 ----
__global__ __launch_bounds__(256, 4) void k_states(
    const _Float16* __restrict__ convh, const float* __restrict__ dtb,
    const float* __restrict__ dacb, _Float16* __restrict__ statesT) {
  __shared__ __align__(16) _Float16 sA[64 * 72];    // XW^T [p][s] swizzled
  __shared__ __align__(16) _Float16 sB2[128 * 72];  // B^T [n][s] swizzled
  __shared__ float sFac[CLEN];
  int h = blockIdx.x, z = blockIdx.y, bk = blockIdx.z;
  int b = bk >> 2, kd = bk & 3;
  int t = threadIdx.x, lane = t & 63, w = t >> 6;
  int acol = lane & 15, koct = lane >> 4;
  size_t dbase = (((size_t)bk * NCH + z) * NHD + h) * CLEN;
  {
    float dac_last = dacb[dbase + CLEN - 1];
    sFac[t] = dtb[dbase + t] * __expf(dac_last - dacb[dbase + t]);
  }
  __syncthreads();
  const _Float16* convb = convh + (size_t)b * LQ * CH640;
  f32x4 zz = {0.f, 0.f, 0.f, 0.f};
  f32x4 acc[8] = {zz, zz, zz, zz, zz, zz, zz, zz};
  for (int st = 0; st < 4; ++st) {
    if (st) __syncthreads();
#pragma unroll
    for (int i = 0; i < 2; ++i) {
      int c = t + i * 256;
      int ss = c >> 3, pp0 = (c & 7) * 8;
      int sg = st * 64 + ss;
      int px = pixof(kd, z * CLEN + sg);
      half8 xv = *(const half8*)&convb[(size_t)px * CH640 + h * 64 + pp0];
      float f = sFac[sg];
#pragma unroll
      for (int u = 0; u < 8; ++u) sA[XWI(pp0 + u, ss)] = (_Float16)((float)xv[u] * f);
    }
#pragma unroll
    for (int i = 0; i < 4; ++i) {
      int c = t + i * 256;
      int ss = c >> 4, n0 = (c & 15) * 8;
      int sg = st * 64 + ss;
      int px = pixof(kd, z * CLEN + sg);
      half8 bv = *(const half8*)&convb[(size_t)px * CH640 + DSSM + n0];
#pragma unroll
      for (int u = 0; u < 8; ++u) sB2[XW2(n0 + u, ss)] = bv[u];
    }
    __syncthreads();
#pragma unroll
    for (int ks = 0; ks < 2; ++ks) {
      int kso = ks * 4 + koct;
      int arow = w * 16 + acol;
      half8 a = *(const half8*)&sA[arow * 72 + ((kso ^ (arow >> 3)) << 3)];
#pragma unroll
      for (int nf = 0; nf < 8; ++nf) {
        int col = nf * 16 + acol;
        half8 bf = *(const half8*)&sB2[col * 72 + (((kso ^ (col >> 3)) & 7) << 3)];
        acc[nf] = __builtin_amdgcn_mfma_f32_16x16x32_f16(a, bf, acc[nf], 0, 0, 0);
      }
    }
  }
  size_t sbase = (((size_t)bk * NCH + z) * NHD + h) * (128 * 64);
  int rbase = koct * 4;
#pragma unroll
  for (int nf = 0; nf < 8; ++nf) {
    int col = nf * 16 + acol;
#pragma unroll
    for (int r = 0; r < 4; ++r)
      statesT[sbase + (size_t)(w * 16 + rbase + r) * 128 + col] = (_Float16)acc[nf][r];
  }
}

// ---- 6. inter-chunk scan (in place on fp16, fp32 carry; 8-way element split) ----
__global__ void k_scan(_Float16* __restrict__ states, const float* __restrict__ dacb) {
  int hs = blockIdx.x;  // h*8 + split
  int h = hs >> 3, sp = hs & 7;
  int k = blockIdx.y, b = blockIdx.z;
  int bk = b * KDIR + k;
  int t = threadIdx.x;
  float carry[4];
#pragma unroll
  for (int j = 0; j < 4; ++j) carry[j] = 0.f;
  for (int z = 0; z < NCH; ++z) {
    float cd = __expf(dacb[(((size_t)bk * NCH + z) * NHD + h) * CLEN + (CLEN - 1)]);
    size_t sbase = (((size_t)bk * NCH + z) * NHD + h) * (128 * 64) + (size_t)sp * 1024;
#pragma unroll
    for (int j = 0; j < 4; ++j) {
      size_t idx = sbase + (size_t)j * 256 + t;
      float sv = (float)states[idx];
      states[idx] = (_Float16)carry[j];
      carry[j] = carry[j] * cd + sv;
    }
  }
}

// ---- 7. y via fp16 MFMA, minimal LDS (only sXW), 6 blocks/CU, no spill ----
__global__ __launch_bounds__(256, 6) void k_y(
    const _Float16* __restrict__ convh, const float* __restrict__ dtb,
    const float* __restrict__ dacb, const _Float16* __restrict__ cbuf,
    const _Float16* __restrict__ prevT, const _Float16* __restrict__ dbuf,
    const float* __restrict__ Ds, _Float16* __restrict__ ybuf) {
  __shared__ __align__(16) _Float16 sXW[64 * 72];
  __shared__ float sdt[CLEN], sdac[CLEN], sFac[CLEN];
  __shared__ float sExpD[64], sRs[64];

  int wg = blockIdx.x;  // 6144 = 8 XCD * 768
  int xid = (wg & 7) * 768 + (wg >> 3);
  int grp = xid / 24, i24 = xid % 24;
  int h = i24 >> 2, si_t = i24 & 3;
  int bk = grp >> 4, z = grp & 15;
  int b = bk >> 2, kd = bk & 3;
  int t = threadIdx.x, lane = t & 63, w = t >> 6;
  int acol = lane & 15, koff = (lane >> 4) * 8;
  int R = w * 16, arow = R + acol, rbase = R + (lane >> 4) * 4;

  size_t dbase = (((size_t)bk * NCH + z) * NHD + h) * CLEN;
  sdt[t] = dtb[dbase + t];
  sdac[t] = dacb[dbase + t];
  __syncthreads();
  float ref = sdac[si_t * 64];
  sFac[t] = __expf(ref - sdac[t]);
  if (t < 64) {
    float d = sdac[si_t * 64 + t];
    sExpD[t] = __expf(d);
    sRs[t] = __expf(d - ref);
  }
  const _Float16* convb = convh + (size_t)b * LQ * CH640;
  const _Float16* pbp = prevT + (((size_t)bk * NCH + z) * NHD + h) * (128 * 64);
  f32x4 zz = {0.f, 0.f, 0.f, 0.f};
  f32x4 accE[4] = {zz, zz, zz, zz};
  f32x4 accI[4] = {zz, zz, zz, zz};
  // ---- y_inter: C and prev fragments straight from global ----
  int pxa = pixof(kd, z * CLEN + si_t * 64 + arow);
#pragma unroll
  for (int ks = 0; ks < 4; ++ks) {
    half8 a = *(const half8*)&convb[(size_t)pxa * CH640 + (DSSM + DST) + ks * 32 + koff];
#pragma unroll
    for (int cg = 0; cg < 4; ++cg) {
      half8 bf = *(const half8*)&pbp[(size_t)(cg * 16 + acol) * 128 + ks * 32 + koff];
      accE[cg] = __builtin_amdgcn_mfma_f32_16x16x32_f16(a, bf, accE[cg], 0, 0, 0);
    }
  }
  __syncthreads();  // sFac/sExpD/sRs ready
  // ---- y_intra off-diagonal ----
  for (int SJ = 0; SJ < si_t; ++SJ) {
#pragma unroll
    for (int i = 0; i < 2; ++i) {
      int c = t + i * 256;
      int ss = c >> 3, pp0 = (c & 7) * 8;
      int sg = SJ * 64 + ss;
      int px = pixof(kd, z * CLEN + sg);
      half8 xv = *(const half8*)&convb[(size_t)px * CH640 + h * 64 + pp0];
      float f = sdt[sg] * sFac[sg];
#pragma unroll
      for (int u = 0; u < 8; ++u)
        sXW[XWI(pp0 + u, ss)] = (_Float16)((float)xv[u] * f);
    }
    __syncthreads();
    size_t cbase = ((size_t)(bk * NCH + z) * 10 + si_t * (si_t + 1) / 2 + SJ) * 4096;
#pragma unroll
    for (int ks = 0; ks < 2; ++ks) {
      half8 a = *(const half8*)&cbuf[cbase + (size_t)arow * 64 + ks * 32 + koff];
      int kso = ks * 4 + (lane >> 4);
#pragma unroll
      for (int cg = 0; cg < 4; ++cg) {
        int col = cg * 16 + acol;
        half8 bf = *(const half8*)&sXW[col * 72 + ((kso ^ (col >> 3)) << 3)];
        accI[cg] = __builtin_amdgcn_mfma_f32_16x16x32_f16(a, bf, accI[cg], 0, 0, 0);
      }
    }
    __syncthreads();
  }
  // scale off-diag partial by per-row decay
  {
    float rsv[4];
#pragma unroll
    for (int r = 0; r < 4; ++r) rsv[r] = sRs[rbase + r];
#pragma unroll
    for (int cg = 0; cg < 4; ++cg)
#pragma unroll
      for (int r = 0; r < 4; ++r) accI[cg][r] *= rsv[r];
  }
  // ---- diagonal tile: A' precomputed in dbuf ----
  {
#pragma unroll
    for (int i = 0; i < 2; ++i) {
      int c = t + i * 256;
      int ss = c >> 3, pp0 = (c & 7) * 8;
      int sg = si_t * 64 + ss;
      int px = pixof(kd, z * CLEN + sg);
      half8 xv = *(const half8*)&convb[(size_t)px * CH640 + h * 64 + pp0];
      float f = sdt[sg];
#pragma unroll
      for (int u = 0; u < 8; ++u)
        sXW[XWI(pp0 + u, ss)] = (_Float16)((float)xv[u] * f);
    }
    __syncthreads();
    size_t db = (((size_t)(bk * NCH + z) * 4 + si_t) * NHD + h) * 4096;
#pragma unroll
    for (int ks = 0; ks < 2; ++ks) {
      half8 a = *(const half8*)&dbuf[db + (size_t)arow * 64 + ks * 32 + koff];
      int kso = ks * 4 + (lane >> 4);
#pragma unroll
      for (int cg = 0; cg < 4; ++cg) {
        int col = cg * 16 + acol;
        half8 bf = *(const half8*)&sXW[col * 72 + ((kso ^ (col >> 3)) << 3)];
        accI[cg] = __builtin_amdgcn_mfma_f32_16x16x32_f16(a, bf, accI[cg], 0, 0, 0);
      }
    }
  }
  // ---- write: y = accI + exp(dac)*accE + D*x ----
  float dsv = Ds[kd * NHD + h];
  float eD[4];
#pragma unroll
  for (int r = 0; r < 4; ++r) eD[r] = sExpD[rbase + r];
#pragma unroll
  for (int cg = 0; cg < 4; ++cg) {
    int col = cg * 16 + acol;
#pragma unroll
    for (int r = 0; r < 4; ++r) {
      int row = rbase + r;
      int tg = z * CLEN + si_t * 64 + row;
      int px = pixof(kd, tg);
      float xv = (float)convb[(size_t)px * CH640 + h * 64 + col];
      float yv = accI[cg][r] + eD[r] * accE[cg][r] + dsv * xv;
      ybuf[((size_t)bk * LQ + tg) * DSSM + h * 64 + col] = (_Float16)yv;
    }
  }
}

// ---- 8. gather + gated RMSNorm + out projection via MFMA (32 rows / block) ----
__global__ __launch_bounds__(256) void k_final(
    const _Float16* __restrict__ yb, const _Float16* __restrict__ zh,
    const float* __restrict__ norm_w, const _Float16* __restrict__ woT,
    float* __restrict__ out) {
  __shared__ __align__(16) _Float16 sG[32 * 392];
  int m0 = blockIdx.x * 32;
  int t = threadIdx.x;
  int row = t >> 3, q = t & 7;
  int m = m0 + row, b = m >> 12, px = m & 4095;
  int tr = ((px & 63) << 6) | (px >> 6);
  int t0 = px, t1 = tr, t2 = 4095 - px, t3 = 4095 - tr;
  size_t b4 = (size_t)b * 4;
  float gbuf[48];
  float sumsq = 0.f;
#pragma unroll
  for (int i = 0; i < 6; ++i) {
    int c0 = q * 48 + i * 8;
    half8 y0 = *(const half8*)&yb[((b4 + 0) * LQ + t0) * DSSM + c0];
    half8 y1 = *(const half8*)&yb[((b4 + 1) * LQ + t1) * DSSM + c0];
    half8 y2 = *(const half8*)&yb[((b4 + 2) * LQ + t2) * DSSM + c0];
    half8 y3 = *(const half8*)&yb[((b4 + 3) * LQ + t3) * DSSM + c0];
    half8 zv8 = *(const half8*)&zh[(size_t)m * DSSM + c0];
#pragma unroll
    for (int u = 0; u < 8; ++u) {
      float zv = (float)zv8[u];
      float g = ((float)y0[u] + (float)y1[u] + (float)y2[u] + (float)y3[u]) *
                (zv / (1.f + __expf(-zv)));
      gbuf[i * 8 + u] = g;
      sumsq += g * g;
    }
  }
  sumsq += __shfl_xor(sumsq, 1);
  sumsq += __shfl_xor(sumsq, 2);
  sumsq += __shfl_xor(sumsq, 4);
  float rstd = rsqrtf(sumsq / (float)DSSM + 1e-5f);
#pragma unroll
  for (int i = 0; i < 6; ++i) {
    int c0 = q * 48 + i * 8;
    half8 gv;
#pragma unroll
    for (int u = 0; u < 8; ++u)
      gv[u] = (_Float16)(gbuf[i * 8 + u] * rstd * norm_w[c0 + u]);
    *(half8*)&sG[row * 392 + c0] = gv;
  }
  __syncthreads();
  int lane = t & 63, w = t >> 6;
  int acol = lane & 15, koff = (lane >> 4) * 8;
  int rt = (w & 1) * 16, cb0 = (w >> 1) * 96;
  f32x4 zz = {0.f, 0.f, 0.f, 0.f};
  f32x4 acc[6] = {zz, zz, zz, zz, zz, zz};
  for (int ks = 0; ks < 12; ++ks) {
    half8 a = *(const half8*)&sG[(rt + acol) * 392 + ks * 32 + koff];
#pragma unroll
    for (int nf = 0; nf < 6; ++nf) {
      half8 bf = *(const half8*)&woT[(size_t)(cb0 + nf * 16 + acol) * 384 + ks * 32 + koff];
      acc[nf] = __builtin_amdgcn_mfma_f32_16x16x32_f16(a, bf, acc[nf], 0, 0, 0);
    }
  }
  int rb = (lane >> 4) * 4;
#pragma unroll
  for (int nf = 0; nf < 6; ++nf) {
    int n = cb0 + nf * 16 + acol;
#pragma unroll
    for (int r = 0; r < 4; ++r)
      out[(size_t)(m0 + rt + rb + r) * DM + n] = acc[nf][r];
  }
}

extern "C" void kernel_launch(void* const* d_in, const int* in_sizes, int n_in,
                              void* d_out, int out_size, void* d_ws, size_t ws_size,
                              hipStream_t stream) {
  const float* u = (const float*)d_in[0];
  const float* W_in = (const float*)d_in[1];
  const float* conv_w = (const float*)d_in[2];
  const float* conv_b = (const float*)d_in[3];
  const float* dt_bias = (const float*)d_in[4];
  const float* A_logs = (const float*)d_in[5];
  const float* Ds = (const float*)d_in[6];
  const float* norm_w = (const float*)d_in[7];
  const float* W_out = (const float*)d_in[8];
  float* out = (float*)d_out;

  float* ws = (float*)d_ws;
  size_t off = 0;
  __half* zh = (__half*)(ws + off); off += (size_t)BQ * LQ * DSSM / 2;
  float* scratch = ws + off; off += 1683456;  // uh+whT region, reused for dt bufs
  _Float16* uh = (_Float16*)scratch;
  _Float16* whT = uh + UH_ELEMS;
  float* dtraw = scratch;                                   // alias (uh dead post-inproj)
  float* dtb = scratch + 98304;
  float* dacb = scratch + 98304 + 393216;
  __half* xbch = (__half*)(ws + off); off += (size_t)BQ * LQ * CH640 / 2;
  float* xdt32 = ws + off; off += (size_t)BQ * LQ * NHD;
  __half* convh = (__half*)(ws + off); off += (size_t)BQ * LQ * CH640 / 2;
  _Float16* statesT = (_Float16*)(ws + off); off += (size_t)BQ * KDIR * NCH * NHD * 128 * 64 / 2;
  __half* ybuf = (__half*)(ws + off); off += (size_t)BQ * KDIR * LQ * DSSM / 2;
  _Float16* dbuf = (_Float16*)(ws + off); off += (size_t)BQ * KDIR * NCH * 4 * NHD * 4096 / 2;
  _Float16* woT = (_Float16*)(ws + off); off += WO_ELEMS / 2;
  _Float16* cbuf = (_Float16*)xbch;  // alias: xbch dead after k_conv

  k_cvt<<<(UH_ELEMS + WT_ELEMS + WO_ELEMS + 255) / 256, 256, 0, stream>>>(u, W_in, W_out, uh, whT, woT);
  k_inproj<<<dim3(9, 128), 256, 0, stream>>>(uh, whT, zh, xbch, xdt32);
  k_conv<<<BQ * LQ, 256, 0, stream>>>(xbch, xdt32, conv_w, conv_b, convh, dtraw);
  k_prep<<<dim3(NCH, KDIR, BQ), 256, 0, stream>>>(dtraw, dt_bias, A_logs, dtb, dacb);
  k_cb<<<dim3(10, NCH, BQ * KDIR), 256, 0, stream>>>((const _Float16*)convh, cbuf);
  k_diag<<<dim3(24, NCH, BQ * KDIR), 256, 0, stream>>>(cbuf, dacb, dbuf);
  k_states<<<dim3(NHD, NCH, BQ * KDIR), 256, 0, stream>>>((const _Float16*)convh, dtb, dacb, statesT);
  k_scan<<<dim3(NHD * 8, KDIR, BQ), 256, 0, stream>>>(statesT, dacb);
  k_y<<<KDIR * NHD * 4 * NCH * BQ, 256, 0, stream>>>((const _Float16*)convh, dtb, dacb,
                                                     (const _Float16*)cbuf, statesT, dbuf, Ds,
                                                     (_Float16*)ybuf);
  k_final<<<BQ * LQ / 32, 256, 0, stream>>>((const _Float16*)ybuf, (const _Float16*)zh,
                                            norm_w, woT, out);
}